// Round 4
// baseline (336.095 us; speedup 1.0000x reference)
//
#include <hip/hip_runtime.h>

namespace {
constexpr int NA    = 5;
constexpr int NCELL = 361;            // 19*19
constexpr int NBOX  = 1805;           // NA * NCELL
constexpr int SORTN = 2048;
constexpr int NT    = 256;            // 4 waves
constexpr int TMAX  = 50;
constexpr float CONF_T = 0.5f;
constexpr float NMS_T  = 0.45f;
constexpr float IOU_T  = 0.5f;
constexpr int NWMAX = 32;             // 64-bit keep/remove words (29 needed)
}

__device__ __constant__ float d_anchw[NA] = {1.3221f, 3.19275f, 5.05587f, 9.47112f, 11.2364f};
__device__ __constant__ float d_anchh[NA] = {1.73145f, 4.00944f, 8.09892f, 4.84053f, 10.0071f};

// One block per batch image; everything fused, NMS state never leaves the CU.
__global__ __launch_bounds__(NT, 1) void k_fused(
    const float* __restrict__ net,    // [B,125,19,19]
    const float* __restrict__ tgt,    // [B,250]
    float4* __restrict__ rawbox,      // ws scratch [B,NBOX]
    int* __restrict__ counters,       // ws: prop, corr, total, done
    float* __restrict__ out)          // [6]
{
    __shared__ unsigned long long skey[SORTN];                    // 16 KB
    __shared__ float X1s[NBOX], Y1s[NBOX], X2s[NBOX], Y2s[NBOX];  // sorted corner SoA
    __shared__ float Ws[NBOX], Hs[NBOX];                          // 6*7220 = 43.3 KB
    __shared__ unsigned long long cw[64];                         // intra-tile colwords
    __shared__ unsigned long long rmw[NWMAX], keepw[NWMAX];
    __shared__ int sM, sNV, sProp, sCorr;

    const int b = blockIdx.x, tid = threadIdx.x;
    const int wv = tid >> 6, lane = tid & 63;
    const float* op = net + (size_t)b * (NA * 25 * NCELL);
    float4* rb = rawbox + (size_t)b * NBOX;

    if (tid == 0) { sM = 0; sProp = 0; sCorr = 0; }
    if (tid < NWMAX) { rmw[tid] = 0ull; keepw[tid] = 0ull; }

    // ---- decode: raw boxes to global scratch, sort keys to LDS ----
    for (int n = tid; n < NBOX; n += NT) {
        int a = n / NCELL;
        int r = n - a * NCELL;
        int y = r / 19;
        int x = r - y * 19;
        int base = a * 25 * NCELL + r;
        float t0 = op[base];
        float t1 = op[base + 1 * NCELL];
        float t2 = op[base + 2 * NCELL];
        float t3 = op[base + 3 * NCELL];
        float t4 = op[base + 4 * NCELL];
        float cx = (1.0f / (1.0f + expf(-t0)) + (float)x) / 19.0f;
        float cy = (1.0f / (1.0f + expf(-t1)) + (float)y) / 19.0f;
        float bw = expf(t2) * (d_anchw[a] / 19.0f);
        float bh = expf(t3) * (d_anchh[a] / 19.0f);
        float det = 1.0f / (1.0f + expf(-t4));
        rb[n] = make_float4(cx, cy, bw, bh);
        // ascending sort key == stable argsort(-det)
        skey[n] = ((unsigned long long)(~__float_as_uint(det)) << 32) | (unsigned)n;
    }
    for (int n = NBOX + tid; n < SORTN; n += NT) skey[n] = ~0ull;
    __syncthreads();

    // ---- register-blocked bitonic sort: 256 thr x 8 elems (verified in R3) ----
    {
        unsigned long long v[8];
        const int base8 = tid << 3;
        auto cas = [&](int x, int y, bool up) {
            unsigned long long a = v[x], c = v[y];
            if ((a > c) == up) { v[x] = c; v[y] = a; }
        };
        {
            #pragma unroll
            for (int p = 0; p < 8; ++p) v[p] = skey[base8 + p];
            cas(0,1,true); cas(2,3,false); cas(4,5,true); cas(6,7,false);
            cas(0,2,true); cas(1,3,true); cas(4,6,false); cas(5,7,false);
            cas(0,1,true); cas(2,3,true); cas(4,5,false); cas(6,7,false);
            bool u8 = ((base8 & 8) == 0);
            cas(0,4,u8); cas(1,5,u8); cas(2,6,u8); cas(3,7,u8);
            cas(0,2,u8); cas(1,3,u8); cas(4,6,u8); cas(5,7,u8);
            cas(0,1,u8); cas(2,3,u8); cas(4,5,u8); cas(6,7,u8);
            #pragma unroll
            for (int p = 0; p < 8; ++p) skey[base8 + p] = v[p];
        }
        __syncthreads();
        for (unsigned k = 16; k <= SORTN; k <<= 1) {
            for (unsigned j = k >> 1; j >= 8; j >>= 1) {
                #pragma unroll
                for (int c = 0; c < 4; ++c) {
                    unsigned m = (tid << 2) + c;
                    unsigned i = ((m & ~(j - 1)) << 1) | (m & (j - 1));
                    unsigned p = i | j;
                    bool up = ((i & k) == 0);
                    unsigned long long a = skey[i], c2 = skey[p];
                    if ((a > c2) == up) { skey[i] = c2; skey[p] = a; }
                }
                __syncthreads();
            }
            {
                #pragma unroll
                for (int p = 0; p < 8; ++p) v[p] = skey[base8 + p];
                bool up = ((base8 & k) == 0);
                cas(0,4,up); cas(1,5,up); cas(2,6,up); cas(3,7,up);
                cas(0,2,up); cas(1,3,up); cas(4,6,up); cas(5,7,up);
                cas(0,1,up); cas(2,3,up); cas(4,5,up); cas(6,7,up);
                #pragma unroll
                for (int p = 0; p < 8; ++p) skey[base8 + p] = v[p];
            }
            __syncthreads();
        }
    }

    // ---- gather to sorted corner SoA in LDS, find M (conf>0.5 prefix) ----
    for (int p = tid; p < NBOX; p += NT) {
        unsigned long long kk = skey[p];
        int n = (int)(unsigned)(kk & 0xffffffffull);
        float det = __uint_as_float(~(unsigned)(kk >> 32));
        float4 bx = rb[n];
        X1s[p] = bx.x - 0.5f * bx.z;
        Y1s[p] = bx.y - 0.5f * bx.w;
        X2s[p] = bx.x + 0.5f * bx.z;
        Y2s[p] = bx.y + 0.5f * bx.w;
        Ws[p]  = bx.z;
        Hs[p]  = bx.w;
        if (det > CONF_T) {
            float dn = 0.0f;
            if (p + 1 < NBOX) dn = __uint_as_float(~(unsigned)(skey[p + 1] >> 32));
            if (!(dn > CONF_T)) sM = p + 1;      // unique boundary thread
        }
    }
    if (wv == 1) {       // GT count via ballot (first row with cx==0)
        float cxv = (lane < TMAX) ? tgt[b * 250 + lane * 5 + 1] : 0.0f;
        unsigned long long bm = __ballot(cxv != 0.0f);
        unsigned long long inv = (~bm) & ((1ull << TMAX) - 1);
        if (lane == 0) sNV = inv ? (__ffsll((long long)inv) - 1) : TMAX;
    }
    __syncthreads();
    const int M = sM;
    const int nwa = (M + 63) >> 6;

    // ---- tiled greedy NMS: ballot sweep, no memory on the serial chain ----
    for (int t = 0; t < nwa; ++t) {
        const int t0 = t << 6;
        // (a) intra-tile colwords: bit r of cw[c-t0] = "row r suppresses col c"
        {
            int r = t0 + lane;
            int rr = (r < NBOX) ? r : (NBOX - 1);
            float rx1 = X1s[rr], ry1 = Y1s[rr], rx2 = X2s[rr], ry2 = Y2s[rr];
            float rw = Ws[rr], rh = Hs[rr], rarea = rw * rh;
            for (int k = 0; k < 16; ++k) {
                int c = t0 + (wv << 4) + k;
                bool cok = c < M;
                int cc = cok ? c : 0;
                float bx2 = X2s[cc], by2 = Y2s[cc], bx1 = X1s[cc], by1 = Y1s[cc];
                float bw = Ws[cc], bh = Hs[cc];
                float uw = fmaxf(rx2, bx2) - fminf(rx1, bx1);
                float uh = fmaxf(ry2, by2) - fminf(ry1, by1);
                float cww = rw + bw - uw, chh = rh + bh - uh;
                float ca = cww * chh;
                bool p = (r < c) && cok && (r < M) && (cww > 0.0f) && (chh > 0.0f)
                         && (ca > NMS_T * (rarea + bw * bh - ca));
                unsigned long long m = __ballot(p);
                if (lane == 0) cw[(wv << 4) + k] = m;
            }
        }
        __syncthreads();
        // (b) serial 64-step sweep (wave 0): pure register/ballot chain
        if (wv == 0) {
            unsigned long long colw = cw[lane];
            unsigned long long cur = rmw[t];
            #pragma unroll
            for (int i = 0; i < 64; ++i) {
                bool kept = ((cur >> i) & 1ull) == 0ull;
                bool p = kept && (((colw >> i) & 1ull) != 0ull);
                cur |= __ballot(p);
            }
            if (lane == 0) {
                int rem = M - t0;
                unsigned long long vm = (rem >= 64) ? ~0ull : ((1ull << rem) - 1ull);
                rmw[t] = cur;
                keepw[t] = (~cur) & vm;
            }
        }
        __syncthreads();
        // (c) kept rows of this tile suppress cols in later tiles (all 4 waves)
        {
            unsigned long long kwt = keepw[t];      // uniform
            if (kwt) {
                for (int wb = t + 1; wb < nwa; wb += 16) {
                    float cx1[4], cy1[4], cx2[4], cy2[4], cwd[4], chd[4];
                    bool acc[4], jok[4];
                    #pragma unroll
                    for (int c = 0; c < 4; ++c) {
                        int w = wb + wv + (c << 2);
                        int j = (w << 6) + lane;
                        bool ok = (w < nwa) && (j < M);
                        jok[c] = ok; acc[c] = false;
                        int js = ok ? j : 0;
                        cx1[c] = X1s[js]; cy1[c] = Y1s[js];
                        cx2[c] = X2s[js]; cy2[c] = Y2s[js];
                        cwd[c] = Ws[js];  chd[c] = Hs[js];
                    }
                    unsigned long long kb = kwt;
                    while (kb) {
                        int i = __ffsll((long long)kb) - 1; kb &= kb - 1;
                        int r = t0 + i;
                        float rx1 = X1s[r], ry1 = Y1s[r], rx2 = X2s[r], ry2 = Y2s[r];
                        float rw = Ws[r], rh = Hs[r], rarea = rw * rh;
                        #pragma unroll
                        for (int c = 0; c < 4; ++c) {
                            float uw = fmaxf(rx2, cx2[c]) - fminf(rx1, cx1[c]);
                            float uh = fmaxf(ry2, cy2[c]) - fminf(ry1, cy1[c]);
                            float cww = rw + cwd[c] - uw, chh = rh + chd[c] - uh;
                            float ca = cww * chh;
                            bool p = (cww > 0.0f) && (chh > 0.0f)
                                     && (ca > NMS_T * (rarea + cwd[c] * chd[c] - ca));
                            acc[c] = acc[c] | p;
                        }
                    }
                    #pragma unroll
                    for (int c = 0; c < 4; ++c) {
                        unsigned long long m = __ballot(acc[c] && jok[c]);
                        int w = wb + wv + (c << 2);
                        if (lane == 0 && w < nwa && m) rmw[w] |= m;  // word exclusive per wave
                    }
                }
            }
        }
        __syncthreads();
    }

    // ---- proposals ----
    if (wv == 0) {
        unsigned long long kv = (lane < NWMAX) ? keepw[lane] : 0ull;
        int pc = __popcll(kv);
        for (int d = 32; d > 0; d >>= 1) pc += __shfl_down(pc, d, 64);
        if (lane == 0) sProp = pc;
    }

    // ---- GT matching: wave per GT row, lanes stripe boxes ----
    const int nv = sNV;
    for (int t = wv; t < nv; t += 4) {
        const float* g = tgt + b * 250 + t * 5;
        float gcx = g[1], gcy = g[2], gw = g[3], gh = g[4];
        float gx1 = gcx - 0.5f * gw, gx2 = gcx + 0.5f * gw;
        float gy1 = gcy - 0.5f * gh, gy2 = gcy + 0.5f * gh;
        float garea = gw * gh;
        float best = 0.0f;
        for (int j = lane; j < M; j += 64) {
            if (!((keepw[j >> 6] >> (j & 63)) & 1ull)) continue;
            float bw = Ws[j], bh = Hs[j];
            float uw = fmaxf(gx2, X2s[j]) - fminf(gx1, X1s[j]);
            float uh = fmaxf(gy2, Y2s[j]) - fminf(gy1, Y1s[j]);
            float cww = gw + bw - uw, chh = gh + bh - uh;
            float ca = (cww > 0.0f && chh > 0.0f) ? cww * chh : 0.0f;
            float ua = garea + bw * bh - ca;
            best = fmaxf(best, ca / ua);
        }
        for (int d = 32; d > 0; d >>= 1) best = fmaxf(best, __shfl_down(best, d, 64));
        if (lane == 0 && best > IOU_T) atomicAdd(&sCorr, 1);
    }
    __syncthreads();

    // ---- epilogue: device counters; last block writes the 6 outputs ----
    if (tid == 0) {
        atomicAdd(counters + 0, sProp);
        atomicAdd(counters + 1, sCorr);
        atomicAdd(counters + 2, nv);
        __threadfence();
        int done = atomicAdd(counters + 3, 1);
        if (done == 7) {
            float prop  = (float)atomicAdd(counters + 0, 0);
            float corr  = (float)atomicAdd(counters + 1, 0);
            float total = (float)atomicAdd(counters + 2, 0);
            float prec = corr / (prop + 1e-6f);
            float rec  = corr / (total + 1e-6f);
            float fs   = 2.0f * prec * rec / (prec + rec + 1e-6f);
            out[0] = total;
            out[1] = prop;
            out[2] = corr;
            out[3] = prec;
            out[4] = rec;
            out[5] = fs;
        }
    }
}

extern "C" void kernel_launch(void* const* d_in, const int* in_sizes, int n_in,
                              void* d_out, int out_size, void* d_ws, size_t ws_size,
                              hipStream_t stream) {
    const float* net = (const float*)d_in[0];   // [8,125,19,19] f32
    const float* tgt = (const float*)d_in[1];   // [8,250] f32
    char* ws = (char*)d_ws;
    int* counters = (int*)ws;                    // 4 ints
    float4* rawbox = (float4*)(ws + 256);        // 8*1805*16 B

    hipMemsetAsync(counters, 0, 16, stream);
    k_fused<<<8, NT, 0, stream>>>(net, tgt, rawbox, counters, (float*)d_out);
}

// Round 5
// 196.034 us; speedup vs baseline: 1.7145x; 1.7145x over previous
//
#include <hip/hip_runtime.h>

namespace {
constexpr int NA    = 5;
constexpr int NCELL = 361;            // 19*19
constexpr int NBOX  = 1805;           // NA * NCELL
constexpr int SORTN = 2048;
constexpr int NT1   = 256;            // K1: 8 elems/thread register bitonic
constexpr int TMAX  = 50;
constexpr float CONF_T = 0.5f;
constexpr float NMS_T  = 0.45f;
constexpr float IOU_T  = 0.5f;
constexpr int NWMAX   = 32;           // keep/remove words (29 needed)
constexpr int ROWPAD  = 1856;         // padded row dim (>= 28*64+127, mult of 64)
constexpr int SOA_STRIDE = ROWPAD;
constexpr int SOA_ARR    = 8 * SOA_STRIDE;
// ws layout (bytes)
constexpr size_t WS_COUNT = 0;        // 4 ints: prop, corr, total, done
constexpr size_t WS_M     = 64;       // 8 ints
constexpr size_t WS_SOA   = 256;      // 6 * SOA_ARR floats = 356,352 B
constexpr size_t WS_SUP   = 360448;   // 8 * 32 * ROWPAD * 8 = 3,801,088 B
}

__device__ __constant__ float d_anchw[NA] = {1.3221f, 3.19275f, 5.05587f, 9.47112f, 11.2364f};
__device__ __constant__ float d_anchh[NA] = {1.73145f, 4.00944f, 8.09892f, 4.84053f, 10.0071f};

__device__ inline unsigned long long shflw(unsigned long long v, int src) {
    int lo = __shfl((int)(unsigned)(v & 0xffffffffull), src, 64);
    int hi = __shfl((int)(unsigned)(v >> 32), src, 64);
    return ((unsigned long long)(unsigned)hi << 32) | (unsigned)lo;
}
__device__ inline unsigned long long shflx64(unsigned long long v, int m) {
    int lo = __shfl_xor((int)(unsigned)(v & 0xffffffffull), m, 64);
    int hi = __shfl_xor((int)(unsigned)(v >> 32), m, 64);
    return ((unsigned long long)(unsigned)hi << 32) | (unsigned)lo;
}

// ---- K1: decode + register-blocked bitonic sort + sorted SoA to global ----
__global__ __launch_bounds__(NT1, 1) void k_decode_sort(
    const float* __restrict__ net, float* __restrict__ soa,
    int* __restrict__ Marr, int* __restrict__ counters)
{
    __shared__ unsigned long long skey[SORTN];   // 16 KB
    __shared__ float4 sbox[NBOX];                // 28.9 KB
    __shared__ int sM;
    const int b = blockIdx.x, tid = threadIdx.x;
    const float* op = net + (size_t)b * (NA * 25 * NCELL);
    if (tid == 0) sM = 0;
    if (b == 0 && tid < 4) counters[tid] = 0;    // replaces memset dispatch

    for (int n = tid; n < NBOX; n += NT1) {
        int a = n / NCELL;
        int r = n - a * NCELL;
        int y = r / 19;
        int x = r - y * 19;
        int base = a * 25 * NCELL + r;
        float t0 = op[base];
        float t1 = op[base + 1 * NCELL];
        float t2 = op[base + 2 * NCELL];
        float t3 = op[base + 3 * NCELL];
        float t4 = op[base + 4 * NCELL];
        float cx = (1.0f / (1.0f + expf(-t0)) + (float)x) / 19.0f;
        float cy = (1.0f / (1.0f + expf(-t1)) + (float)y) / 19.0f;
        float bw = expf(t2) * (d_anchw[a] / 19.0f);
        float bh = expf(t3) * (d_anchh[a] / 19.0f);
        float det = 1.0f / (1.0f + expf(-t4));
        sbox[n] = make_float4(cx, cy, bw, bh);
        skey[n] = ((unsigned long long)(~__float_as_uint(det)) << 32) | (unsigned)n;
    }
    for (int n = NBOX + tid; n < SORTN; n += NT1) skey[n] = ~0ull;
    __syncthreads();

    unsigned long long v[8];
    const int base8 = tid << 3;
    auto cas = [&](int x, int y, bool up) {
        unsigned long long a = v[x], c = v[y];
        if ((a > c) == up) { v[x] = c; v[y] = a; }
    };
    {
        #pragma unroll
        for (int p = 0; p < 8; ++p) v[p] = skey[base8 + p];
        cas(0,1,true); cas(2,3,false); cas(4,5,true); cas(6,7,false);
        cas(0,2,true); cas(1,3,true); cas(4,6,false); cas(5,7,false);
        cas(0,1,true); cas(2,3,true); cas(4,5,false); cas(6,7,false);
        bool u8 = ((base8 & 8) == 0);
        cas(0,4,u8); cas(1,5,u8); cas(2,6,u8); cas(3,7,u8);
        cas(0,2,u8); cas(1,3,u8); cas(4,6,u8); cas(5,7,u8);
        cas(0,1,u8); cas(2,3,u8); cas(4,5,u8); cas(6,7,u8);
        #pragma unroll
        for (int p = 0; p < 8; ++p) skey[base8 + p] = v[p];
    }
    __syncthreads();
    for (unsigned k = 16; k <= SORTN; k <<= 1) {
        for (unsigned j = k >> 1; j >= 8; j >>= 1) {
            #pragma unroll
            for (int c = 0; c < 4; ++c) {
                unsigned m = (tid << 2) + c;
                unsigned i = ((m & ~(j - 1)) << 1) | (m & (j - 1));
                unsigned p = i | j;
                bool up = ((i & k) == 0);
                unsigned long long a = skey[i], c2 = skey[p];
                if ((a > c2) == up) { skey[i] = c2; skey[p] = a; }
            }
            __syncthreads();
        }
        {
            #pragma unroll
            for (int p = 0; p < 8; ++p) v[p] = skey[base8 + p];
            bool up = ((base8 & k) == 0);
            cas(0,4,up); cas(1,5,up); cas(2,6,up); cas(3,7,up);
            cas(0,2,up); cas(1,3,up); cas(4,6,up); cas(5,7,up);
            cas(0,1,up); cas(2,3,up); cas(4,5,up); cas(6,7,up);
            #pragma unroll
            for (int p = 0; p < 8; ++p) skey[base8 + p] = v[p];
        }
        __syncthreads();
    }

    float* X1 = soa + 0 * SOA_ARR + b * SOA_STRIDE;
    float* Y1 = soa + 1 * SOA_ARR + b * SOA_STRIDE;
    float* X2 = soa + 2 * SOA_ARR + b * SOA_STRIDE;
    float* Y2 = soa + 3 * SOA_ARR + b * SOA_STRIDE;
    float* Wd = soa + 4 * SOA_ARR + b * SOA_STRIDE;
    float* Hd = soa + 5 * SOA_ARR + b * SOA_STRIDE;
    for (int p = tid; p < NBOX; p += NT1) {
        unsigned long long kk = skey[p];
        int n = (int)(unsigned)(kk & 0xffffffffull);
        float det = __uint_as_float(~(unsigned)(kk >> 32));
        float4 bx = sbox[n];
        X1[p] = bx.x - 0.5f * bx.z;
        Y1[p] = bx.y - 0.5f * bx.w;
        X2[p] = bx.x + 0.5f * bx.z;
        Y2[p] = bx.y + 0.5f * bx.w;
        Wd[p] = bx.z;
        Hd[p] = bx.w;
        if (det > CONF_T) {
            float dn = 0.0f;
            if (p + 1 < NBOX) dn = __uint_as_float(~(unsigned)(skey[p + 1] >> 32));
            if (!(dn > CONF_T)) sM = p + 1;      // unique boundary thread
        }
    }
    __syncthreads();
    if (tid == 0) Marr[b] = sM;
}

// ---- K2: suppression words, transposed supT[b][word][row]; XCD swizzle ----
__global__ __launch_bounds__(256) void k_iou_maskT(
    const float* __restrict__ soa, const int* __restrict__ Marr,
    unsigned long long* __restrict__ supT)
{
    const int blk  = blockIdx.x;
    const int b    = blk & 7;
    const int lane = threadIdx.x & 63;
    const int i    = (blk >> 3) * 4 + (threadIdx.x >> 6);
    const int M = Marr[b];
    if (i >= M) return;
    const float* X1 = soa + 0 * SOA_ARR + b * SOA_STRIDE;
    const float* Y1 = soa + 1 * SOA_ARR + b * SOA_STRIDE;
    const float* X2 = soa + 2 * SOA_ARR + b * SOA_STRIDE;
    const float* Y2 = soa + 3 * SOA_ARR + b * SOA_STRIDE;
    const float* Wd = soa + 4 * SOA_ARR + b * SOA_STRIDE;
    const float* Hd = soa + 5 * SOA_ARR + b * SOA_STRIDE;
    float ax1 = X1[i], ay1 = Y1[i], ax2 = X2[i], ay2 = Y2[i];
    float aw = Wd[i], ah = Hd[i], aarea = aw * ah;
    const int nch = (M + 63) >> 6;
    unsigned long long myw = 0;
    for (int w = 0; w < nch; ++w) {
        int j = (w << 6) + lane;
        bool pred = false;
        if (j > i && j < M) {
            float bw = Wd[j], bh = Hd[j];
            float uw = fmaxf(ax2, X2[j]) - fminf(ax1, X1[j]);
            float uh = fmaxf(ay2, Y2[j]) - fminf(ay1, Y1[j]);
            float cw = aw + bw - uw;
            float ch = ah + bh - uh;
            if (cw > 0.0f && ch > 0.0f) {
                float ca = cw * ch;
                float ua = aarea + bw * bh - ca;
                pred = ca > NMS_T * ua;          // iou > thresh
            }
        }
        unsigned long long m = __ballot(pred);
        if (w == lane) myw = m;
    }
    if (lane < nch)
        supT[((size_t)b * 32 + lane) * ROWPAD + i] = myw;
}

// ---- K3: register-chain greedy sweep + coalesced future-OR + GT match ----
__global__ __launch_bounds__(256, 1) void k_sweep(
    const float* __restrict__ soa, const float* __restrict__ tgt,
    const int* __restrict__ Marr, const unsigned long long* __restrict__ supT,
    int* __restrict__ counters, float* __restrict__ out)
{
    __shared__ unsigned long long rmw[NWMAX], keepw[NWMAX];
    __shared__ int sNV, sCorr, sProp;
    const int b = blockIdx.x, tid = threadIdx.x;
    const int wv = tid >> 6, lane = tid & 63;
    const int M = Marr[b];
    const int nwa = (M + 63) >> 6;
    const unsigned long long* sb = supT + (size_t)b * 32 * ROWPAD;

    if (tid < NWMAX) { rmw[tid] = 0ull; keepw[tid] = 0ull; }
    if (tid == 0) { sCorr = 0; sProp = 0; }
    if (wv == 1) {       // GT count via ballot (first row with cx==0)
        float cxv = (lane < TMAX) ? tgt[b * 250 + lane * 5 + 1] : 0.0f;
        unsigned long long bm = __ballot(cxv != 0.0f);
        unsigned long long inv = (~bm) & ((1ull << TMAX) - 1);
        if (lane == 0) sNV = inv ? (__ffsll((long long)inv) - 1) : TMAX;
    }
    __syncthreads();

    int pcTot = 0;
    unsigned long long diag = 0;
    if (wv == 0 && nwa > 0) diag = sb[lane];     // tile 0 diag word
    for (int t = 0; t < nwa; ++t) {
        if (wv == 0) {
            // serial greedy sweep for tile t — pure register/shuffle chain
            unsigned long long cur = rmw[t];
            int rem = M - (t << 6);
            unsigned long long vm = (rem >= 64) ? ~0ull : ((1ull << rem) - 1ull);
            unsigned long long live = vm & ~cur;
            while (live) {
                int i = __ffsll((long long)live) - 1;
                unsigned long long w64 = shflw(diag, i);  // row i's intra-tile word
                cur |= w64;
                live &= ~w64;
                live &= ~(1ull << i);
            }
            unsigned long long kp = vm & ~cur;
            pcTot += __popcll(kp);
            if (lane == 0) keepw[t] = kp;
            // prefetch next tile's diag (completes during phase c)
            int tn = (t + 1 < nwa) ? t + 1 : t;
            diag = sb[(size_t)tn * ROWPAD + (tn << 6) + lane];
        }
        __syncthreads();
        // phase c: kept rows of tile t suppress cols in future words.
        // one coalesced 512B load + 6-step shuffle-OR reduce per word.
        {
            unsigned long long kmt = keepw[t];
            int t0 = t << 6;
            for (int w = t + 1 + wv; w < nwa; w += 4) {
                unsigned long long vv = sb[(size_t)w * ROWPAD + t0 + lane];
                unsigned long long contrib = ((kmt >> lane) & 1ull) ? vv : 0ull;
                contrib |= shflx64(contrib, 1);
                contrib |= shflx64(contrib, 2);
                contrib |= shflx64(contrib, 4);
                contrib |= shflx64(contrib, 8);
                contrib |= shflx64(contrib, 16);
                contrib |= shflx64(contrib, 32);
                if (lane == 0) rmw[w] |= contrib;   // word owned by this wave this tile
            }
        }
        __syncthreads();
    }
    if (wv == 0 && lane == 0) sProp = pcTot;
    __syncthreads();

    // ---- GT matching: wave per GT row, branchless so loads pipeline ----
    const float* X1 = soa + 0 * SOA_ARR + b * SOA_STRIDE;
    const float* Y1 = soa + 1 * SOA_ARR + b * SOA_STRIDE;
    const float* X2 = soa + 2 * SOA_ARR + b * SOA_STRIDE;
    const float* Y2 = soa + 3 * SOA_ARR + b * SOA_STRIDE;
    const float* Wd = soa + 4 * SOA_ARR + b * SOA_STRIDE;
    const float* Hd = soa + 5 * SOA_ARR + b * SOA_STRIDE;
    const int nv = sNV;
    for (int t = wv; t < nv; t += 4) {
        const float* g = tgt + b * 250 + t * 5;
        float gcx = g[1], gcy = g[2], gw = g[3], gh = g[4];
        float gx1 = gcx - 0.5f * gw, gx2 = gcx + 0.5f * gw;
        float gy1 = gcy - 0.5f * gh, gy2 = gcy + 0.5f * gh;
        float garea = gw * gh;
        float best = 0.0f;
        for (int j0 = 0; j0 < M; j0 += 64) {
            int j = j0 + lane;
            bool ok = (j < M) && ((keepw[j0 >> 6] >> lane) & 1ull);
            int js = (j < NBOX) ? j : (NBOX - 1);
            float bw = Wd[js], bh = Hd[js];
            float uw = fmaxf(gx2, X2[js]) - fminf(gx1, X1[js]);
            float uh = fmaxf(gy2, Y2[js]) - fminf(gy1, Y1[js]);
            float cww = gw + bw - uw, chh = gh + bh - uh;
            float ca = (cww > 0.0f && chh > 0.0f) ? cww * chh : 0.0f;
            float ua = garea + bw * bh - ca;
            float iou = ca / ua;
            best = fmaxf(best, ok ? iou : 0.0f);
        }
        for (int d = 32; d > 0; d >>= 1) best = fmaxf(best, __shfl_down(best, d, 64));
        if (lane == 0 && best > IOU_T) atomicAdd(&sCorr, 1);
    }
    __syncthreads();

    if (tid == 0) {
        atomicAdd(counters + 0, sProp);
        atomicAdd(counters + 1, sCorr);
        atomicAdd(counters + 2, nv);
        __threadfence();
        int done = atomicAdd(counters + 3, 1);
        if (done == 7) {
            float prop  = (float)atomicAdd(counters + 0, 0);
            float corr  = (float)atomicAdd(counters + 1, 0);
            float total = (float)atomicAdd(counters + 2, 0);
            float prec = corr / (prop + 1e-6f);
            float rec  = corr / (total + 1e-6f);
            float fs   = 2.0f * prec * rec / (prec + rec + 1e-6f);
            out[0] = total;
            out[1] = prop;
            out[2] = corr;
            out[3] = prec;
            out[4] = rec;
            out[5] = fs;
        }
    }
}

extern "C" void kernel_launch(void* const* d_in, const int* in_sizes, int n_in,
                              void* d_out, int out_size, void* d_ws, size_t ws_size,
                              hipStream_t stream) {
    const float* net = (const float*)d_in[0];   // [8,125,19,19] f32
    const float* tgt = (const float*)d_in[1];   // [8,250] f32
    char* ws = (char*)d_ws;
    int* counters = (int*)(ws + WS_COUNT);
    int* Marr     = (int*)(ws + WS_M);
    float* soa    = (float*)(ws + WS_SOA);
    unsigned long long* supT = (unsigned long long*)(ws + WS_SUP);

    k_decode_sort<<<8, NT1, 0, stream>>>(net, soa, Marr, counters);
    int rowblocks = (NBOX + 3) / 4;              // 452
    k_iou_maskT<<<rowblocks * 8, 256, 0, stream>>>(soa, Marr, supT);
    k_sweep<<<8, 256, 0, stream>>>(soa, tgt, Marr, supT, counters, (float*)d_out);
}

// Round 6
// 141.303 us; speedup vs baseline: 2.3785x; 1.3873x over previous
//
#include <hip/hip_runtime.h>

namespace {
constexpr int NA    = 5;
constexpr int NCELL = 361;            // 19*19
constexpr int NBOX  = 1805;           // NA * NCELL
constexpr int SORTN = 2048;
constexpr int NT1   = 256;            // K1: 8 elems/thread register bitonic
constexpr int TMAX  = 50;
constexpr float CONF_T = 0.5f;
constexpr float NMS_T  = 0.45f;
constexpr float IOU_T  = 0.5f;
constexpr int NWMAX   = 32;           // keep/remove words (29 needed)
constexpr int ROWPAD  = 1856;         // padded row dim (mult of 64)
constexpr int SOA_STRIDE = ROWPAD;
constexpr int SOA_ARR    = 8 * SOA_STRIDE;
// ws layout (bytes)
constexpr size_t WS_COUNT = 0;        // 4 ints: prop, corr, total, done
constexpr size_t WS_M     = 64;       // 8 ints
constexpr size_t WS_SOA   = 256;      // 6 * SOA_ARR floats = 356,352 B
constexpr size_t WS_SUP   = 360448;   // 8 * 32 * ROWPAD * 8 = 3,801,088 B
}

__device__ __constant__ float d_anchw[NA] = {1.3221f, 3.19275f, 5.05587f, 9.47112f, 11.2364f};
__device__ __constant__ float d_anchh[NA] = {1.73145f, 4.00944f, 8.09892f, 4.84053f, 10.0071f};

__device__ inline unsigned long long shflx64(unsigned long long v, int m) {
    int lo = __shfl_xor((int)(unsigned)(v & 0xffffffffull), m, 64);
    int hi = __shfl_xor((int)(unsigned)(v >> 32), m, 64);
    return ((unsigned long long)(unsigned)hi << 32) | (unsigned)lo;
}
// uniform-index 64-bit readlane: ~3 cyc vs ~60-80 cyc for ds_bpermute shuffles
__device__ inline unsigned long long rdlane64(unsigned long long v, int l) {
    unsigned lo = (unsigned)__builtin_amdgcn_readlane((int)(unsigned)(v & 0xffffffffull), l);
    unsigned hi = (unsigned)__builtin_amdgcn_readlane((int)(unsigned)(v >> 32), l);
    return ((unsigned long long)hi << 32) | lo;
}

// ---- K1: decode + register-blocked bitonic sort + sorted SoA to global ----
__global__ __launch_bounds__(NT1, 1) void k_decode_sort(
    const float* __restrict__ net, float* __restrict__ soa,
    int* __restrict__ Marr, int* __restrict__ counters)
{
    __shared__ unsigned long long skey[SORTN];   // 16 KB
    __shared__ float4 sbox[NBOX];                // 28.9 KB
    __shared__ int sM;
    const int b = blockIdx.x, tid = threadIdx.x;
    const float* op = net + (size_t)b * (NA * 25 * NCELL);
    if (tid == 0) sM = 0;
    if (b == 0 && tid < 4) counters[tid] = 0;    // replaces memset dispatch

    for (int n = tid; n < NBOX; n += NT1) {
        int a = n / NCELL;
        int r = n - a * NCELL;
        int y = r / 19;
        int x = r - y * 19;
        int base = a * 25 * NCELL + r;
        float t0 = op[base];
        float t1 = op[base + 1 * NCELL];
        float t2 = op[base + 2 * NCELL];
        float t3 = op[base + 3 * NCELL];
        float t4 = op[base + 4 * NCELL];
        float cx = (1.0f / (1.0f + expf(-t0)) + (float)x) / 19.0f;
        float cy = (1.0f / (1.0f + expf(-t1)) + (float)y) / 19.0f;
        float bw = expf(t2) * (d_anchw[a] / 19.0f);
        float bh = expf(t3) * (d_anchh[a] / 19.0f);
        float det = 1.0f / (1.0f + expf(-t4));
        sbox[n] = make_float4(cx, cy, bw, bh);
        skey[n] = ((unsigned long long)(~__float_as_uint(det)) << 32) | (unsigned)n;
    }
    for (int n = NBOX + tid; n < SORTN; n += NT1) skey[n] = ~0ull;
    __syncthreads();

    unsigned long long v[8];
    const int base8 = tid << 3;
    auto cas = [&](int x, int y, bool up) {
        unsigned long long a = v[x], c = v[y];
        if ((a > c) == up) { v[x] = c; v[y] = a; }
    };
    {
        #pragma unroll
        for (int p = 0; p < 8; ++p) v[p] = skey[base8 + p];
        cas(0,1,true); cas(2,3,false); cas(4,5,true); cas(6,7,false);
        cas(0,2,true); cas(1,3,true); cas(4,6,false); cas(5,7,false);
        cas(0,1,true); cas(2,3,true); cas(4,5,false); cas(6,7,false);
        bool u8 = ((base8 & 8) == 0);
        cas(0,4,u8); cas(1,5,u8); cas(2,6,u8); cas(3,7,u8);
        cas(0,2,u8); cas(1,3,u8); cas(4,6,u8); cas(5,7,u8);
        cas(0,1,u8); cas(2,3,u8); cas(4,5,u8); cas(6,7,u8);
        #pragma unroll
        for (int p = 0; p < 8; ++p) skey[base8 + p] = v[p];
    }
    __syncthreads();
    for (unsigned k = 16; k <= SORTN; k <<= 1) {
        for (unsigned j = k >> 1; j >= 8; j >>= 1) {
            #pragma unroll
            for (int c = 0; c < 4; ++c) {
                unsigned m = (tid << 2) + c;
                unsigned i = ((m & ~(j - 1)) << 1) | (m & (j - 1));
                unsigned p = i | j;
                bool up = ((i & k) == 0);
                unsigned long long a = skey[i], c2 = skey[p];
                if ((a > c2) == up) { skey[i] = c2; skey[p] = a; }
            }
            __syncthreads();
        }
        {
            #pragma unroll
            for (int p = 0; p < 8; ++p) v[p] = skey[base8 + p];
            bool up = ((base8 & k) == 0);
            cas(0,4,up); cas(1,5,up); cas(2,6,up); cas(3,7,up);
            cas(0,2,up); cas(1,3,up); cas(4,6,up); cas(5,7,up);
            cas(0,1,up); cas(2,3,up); cas(4,5,up); cas(6,7,up);
            #pragma unroll
            for (int p = 0; p < 8; ++p) skey[base8 + p] = v[p];
        }
        __syncthreads();
    }

    float* X1 = soa + 0 * SOA_ARR + b * SOA_STRIDE;
    float* Y1 = soa + 1 * SOA_ARR + b * SOA_STRIDE;
    float* X2 = soa + 2 * SOA_ARR + b * SOA_STRIDE;
    float* Y2 = soa + 3 * SOA_ARR + b * SOA_STRIDE;
    float* Wd = soa + 4 * SOA_ARR + b * SOA_STRIDE;
    float* Hd = soa + 5 * SOA_ARR + b * SOA_STRIDE;
    for (int p = tid; p < NBOX; p += NT1) {
        unsigned long long kk = skey[p];
        int n = (int)(unsigned)(kk & 0xffffffffull);
        float det = __uint_as_float(~(unsigned)(kk >> 32));
        float4 bx = sbox[n];
        X1[p] = bx.x - 0.5f * bx.z;
        Y1[p] = bx.y - 0.5f * bx.w;
        X2[p] = bx.x + 0.5f * bx.z;
        Y2[p] = bx.y + 0.5f * bx.w;
        Wd[p] = bx.z;
        Hd[p] = bx.w;
        if (det > CONF_T) {
            float dn = 0.0f;
            if (p + 1 < NBOX) dn = __uint_as_float(~(unsigned)(skey[p + 1] >> 32));
            if (!(dn > CONF_T)) sM = p + 1;      // unique boundary thread
        }
    }
    __syncthreads();
    if (tid == 0) Marr[b] = sM;
}

// ---- K2: suppression words, transposed supT[b][word][row]; XCD swizzle ----
__global__ __launch_bounds__(256) void k_iou_maskT(
    const float* __restrict__ soa, const int* __restrict__ Marr,
    unsigned long long* __restrict__ supT)
{
    const int blk  = blockIdx.x;
    const int b    = blk & 7;
    const int lane = threadIdx.x & 63;
    const int i    = (blk >> 3) * 4 + (threadIdx.x >> 6);
    const int M = Marr[b];
    if (i >= M) return;
    const float* X1 = soa + 0 * SOA_ARR + b * SOA_STRIDE;
    const float* Y1 = soa + 1 * SOA_ARR + b * SOA_STRIDE;
    const float* X2 = soa + 2 * SOA_ARR + b * SOA_STRIDE;
    const float* Y2 = soa + 3 * SOA_ARR + b * SOA_STRIDE;
    const float* Wd = soa + 4 * SOA_ARR + b * SOA_STRIDE;
    const float* Hd = soa + 5 * SOA_ARR + b * SOA_STRIDE;
    float ax1 = X1[i], ay1 = Y1[i], ax2 = X2[i], ay2 = Y2[i];
    float aw = Wd[i], ah = Hd[i], aarea = aw * ah;
    const int nch = (M + 63) >> 6;
    unsigned long long myw = 0;
    for (int w = 0; w < nch; ++w) {
        int j = (w << 6) + lane;
        bool pred = false;
        if (j > i && j < M) {
            float bw = Wd[j], bh = Hd[j];
            float uw = fmaxf(ax2, X2[j]) - fminf(ax1, X1[j]);
            float uh = fmaxf(ay2, Y2[j]) - fminf(ay1, Y1[j]);
            float cw = aw + bw - uw;
            float ch = ah + bh - uh;
            if (cw > 0.0f && ch > 0.0f) {
                float ca = cw * ch;
                float ua = aarea + bw * bh - ca;
                pred = ca > NMS_T * ua;          // iou > thresh
            }
        }
        unsigned long long m = __ballot(pred);
        if (w == lane) myw = m;
    }
    if (lane < nch)
        supT[((size_t)b * 32 + lane) * ROWPAD + i] = myw;
}

// ---- K3: 16-wave sweep. Wave 0: readlane serial chain. Waves 1-15: statically
// owned future-words with cross-barrier prefetch. GT match from LDS SoA. ----
__global__ __launch_bounds__(1024, 1) void k_sweep(
    const float* __restrict__ soa, const float* __restrict__ tgt,
    const int* __restrict__ Marr, const unsigned long long* __restrict__ supT,
    int* __restrict__ counters, float* __restrict__ out)
{
    __shared__ float X1s[NBOX], Y1s[NBOX], X2s[NBOX], Y2s[NBOX];
    __shared__ float Wss[NBOX], Hss[NBOX];               // 43.3 KB
    __shared__ unsigned long long rmw[NWMAX], keepw[NWMAX];
    __shared__ int sNV, sCorr, sProp;
    const int b = blockIdx.x, tid = threadIdx.x;
    const int wv = tid >> 6, lane = tid & 63;
    const int M = Marr[b];
    const int nwa = (M + 63) >> 6;
    const unsigned long long* sb = supT + (size_t)b * 32 * ROWPAD;

    if (tid < NWMAX) { rmw[tid] = 0ull; keepw[tid] = 0ull; }
    if (tid == 0) { sCorr = 0; sProp = 0; }

    // stage sorted SoA into LDS (coalesced)
    {
        const float* X1 = soa + 0 * SOA_ARR + b * SOA_STRIDE;
        const float* Y1 = soa + 1 * SOA_ARR + b * SOA_STRIDE;
        const float* X2 = soa + 2 * SOA_ARR + b * SOA_STRIDE;
        const float* Y2 = soa + 3 * SOA_ARR + b * SOA_STRIDE;
        const float* Wd = soa + 4 * SOA_ARR + b * SOA_STRIDE;
        const float* Hd = soa + 5 * SOA_ARR + b * SOA_STRIDE;
        for (int p = tid; p < NBOX; p += 1024) {
            X1s[p] = X1[p]; Y1s[p] = Y1[p];
            X2s[p] = X2[p]; Y2s[p] = Y2[p];
            Wss[p] = Wd[p]; Hss[p] = Hd[p];
        }
    }
    if (wv == 2) {       // GT count via ballot (first row with cx==0)
        float cxv = (lane < TMAX) ? tgt[b * 250 + lane * 5 + 1] : 0.0f;
        unsigned long long bm = __ballot(cxv != 0.0f);
        unsigned long long inv = (~bm) & ((1ull << TMAX) - 1);
        if (lane == 0) sNV = inv ? (__ffsll((long long)inv) - 1) : TMAX;
    }

    // static word ownership: wave wv owns {wv, wv+15} (covers words 1..28)
    const int w1 = (wv >= 1) ? wv : -1;
    const int w2 = (wv >= 1 && wv + 15 <= 28) ? (wv + 15) : -1;
    unsigned long long cur1 = 0, cur2 = 0, diag = 0;
    if (wv == 0 && nwa > 0) diag = sb[lane];                       // tile0 diag
    if (w1 >= 1 && w1 < nwa) cur1 = sb[(size_t)w1 * ROWPAD + lane]; // tile0 col
    if (w2 >= 1 && w2 < nwa) cur2 = sb[(size_t)w2 * ROWPAD + lane];
    __syncthreads();

    for (int t = 0; t < nwa; ++t) {
        if (wv == 0) {
            // serial greedy sweep for tile t: pure SALU/readlane chain
            unsigned long long cur = rmw[t];
            int rem = M - (t << 6);
            unsigned long long vm = (rem >= 64) ? ~0ull : ((1ull << rem) - 1ull);
            unsigned long long live = vm & ~cur;
            while (live) {
                int i = __ffsll((long long)live) - 1;       // uniform
                unsigned long long w64 = rdlane64(diag, i); // row i intra-tile word
                cur |= w64;
                live &= ~w64;
                live &= ~(1ull << i);
            }
            unsigned long long kp = vm & ~cur;
            if (lane == 0) keepw[t] = kp;
            int tn = t + 1;
            if (tn < nwa) diag = sb[(size_t)tn * ROWPAD + (tn << 6) + lane];
        }
        __syncthreads();                       // keepw[t] visible
        {
            unsigned long long kmt = keepw[t]; // LDS broadcast
            if (w1 > t && w1 < nwa) {
                unsigned long long c = ((kmt >> lane) & 1ull) ? cur1 : 0ull;
                c |= shflx64(c, 1);  c |= shflx64(c, 2);  c |= shflx64(c, 4);
                c |= shflx64(c, 8);  c |= shflx64(c, 16); c |= shflx64(c, 32);
                if (lane == 0) rmw[w1] |= c;   // word exclusively owned
            }
            if (w2 > t && w2 < nwa) {
                unsigned long long c = ((kmt >> lane) & 1ull) ? cur2 : 0ull;
                c |= shflx64(c, 1);  c |= shflx64(c, 2);  c |= shflx64(c, 4);
                c |= shflx64(c, 8);  c |= shflx64(c, 16); c |= shflx64(c, 32);
                if (lane == 0) rmw[w2] |= c;
            }
            // prefetch tile t+1 column — consumed after 2 barriers + sweep
            if (w1 > t + 1 && w1 < nwa) cur1 = sb[(size_t)w1 * ROWPAD + ((t + 1) << 6) + lane];
            if (w2 > t + 1 && w2 < nwa) cur2 = sb[(size_t)w2 * ROWPAD + ((t + 1) << 6) + lane];
        }
        __syncthreads();                       // rmw final for sweep(t+1)
    }

    // proposals
    if (wv == 0) {
        unsigned long long kv = (lane < NWMAX) ? keepw[lane] : 0ull;
        int pc = __popcll(kv);
        for (int d = 32; d > 0; d >>= 1) pc += __shfl_down(pc, d, 64);
        if (lane == 0) sProp = pc;
    }

    // ---- GT matching: 16 waves, branchless, LDS SoA ----
    const int nv = sNV;
    for (int t = wv; t < nv; t += 16) {
        const float* g = tgt + b * 250 + t * 5;
        float gcx = g[1], gcy = g[2], gw = g[3], gh = g[4];
        float gx1 = gcx - 0.5f * gw, gx2 = gcx + 0.5f * gw;
        float gy1 = gcy - 0.5f * gh, gy2 = gcy + 0.5f * gh;
        float garea = gw * gh;
        float best = 0.0f;
        for (int j0 = 0; j0 < M; j0 += 64) {
            int j = j0 + lane;
            bool ok = (j < M) && ((keepw[j0 >> 6] >> lane) & 1ull);
            int js = (j < NBOX) ? j : (NBOX - 1);
            float bw = Wss[js], bh = Hss[js];
            float uw = fmaxf(gx2, X2s[js]) - fminf(gx1, X1s[js]);
            float uh = fmaxf(gy2, Y2s[js]) - fminf(gy1, Y1s[js]);
            float cww = gw + bw - uw, chh = gh + bh - uh;
            float ca = (cww > 0.0f && chh > 0.0f) ? cww * chh : 0.0f;
            float ua = garea + bw * bh - ca;
            float iou = ca / ua;
            best = fmaxf(best, ok ? iou : 0.0f);
        }
        for (int d = 32; d > 0; d >>= 1) best = fmaxf(best, __shfl_down(best, d, 64));
        if (lane == 0 && best > IOU_T) atomicAdd(&sCorr, 1);
    }
    __syncthreads();

    if (tid == 0) {
        atomicAdd(counters + 0, sProp);
        atomicAdd(counters + 1, sCorr);
        atomicAdd(counters + 2, sNV);
        __threadfence();
        int done = atomicAdd(counters + 3, 1);
        if (done == 7) {
            float prop  = (float)atomicAdd(counters + 0, 0);
            float corr  = (float)atomicAdd(counters + 1, 0);
            float total = (float)atomicAdd(counters + 2, 0);
            float prec = corr / (prop + 1e-6f);
            float rec  = corr / (total + 1e-6f);
            float fs   = 2.0f * prec * rec / (prec + rec + 1e-6f);
            out[0] = total;
            out[1] = prop;
            out[2] = corr;
            out[3] = prec;
            out[4] = rec;
            out[5] = fs;
        }
    }
}

extern "C" void kernel_launch(void* const* d_in, const int* in_sizes, int n_in,
                              void* d_out, int out_size, void* d_ws, size_t ws_size,
                              hipStream_t stream) {
    const float* net = (const float*)d_in[0];   // [8,125,19,19] f32
    const float* tgt = (const float*)d_in[1];   // [8,250] f32
    char* ws = (char*)d_ws;
    int* counters = (int*)(ws + WS_COUNT);
    int* Marr     = (int*)(ws + WS_M);
    float* soa    = (float*)(ws + WS_SOA);
    unsigned long long* supT = (unsigned long long*)(ws + WS_SUP);

    k_decode_sort<<<8, NT1, 0, stream>>>(net, soa, Marr, counters);
    int rowblocks = (NBOX + 3) / 4;              // 452
    k_iou_maskT<<<rowblocks * 8, 256, 0, stream>>>(soa, Marr, supT);
    k_sweep<<<8, 1024, 0, stream>>>(soa, tgt, Marr, supT, counters, (float*)d_out);
}

// Round 7
// 139.739 us; speedup vs baseline: 2.4052x; 1.0112x over previous
//
#include <hip/hip_runtime.h>

namespace {
constexpr int NA    = 5;
constexpr int NCELL = 361;            // 19*19
constexpr int NBOX  = 1805;           // NA * NCELL
constexpr int SORTN = 2048;
constexpr int NT1   = 256;            // K1: 8 elems/thread register bitonic
constexpr int TMAX  = 50;
constexpr float CONF_T = 0.5f;
constexpr float NMS_T  = 0.45f;
constexpr float IOU_T  = 0.5f;
constexpr int NWMAX   = 32;           // keep/remove words (29 needed)
constexpr int ROWPAD  = 1856;         // padded row dim (mult of 64)
constexpr int SOA_STRIDE = ROWPAD;
constexpr int SOA_ARR    = 8 * SOA_STRIDE;
// ws layout (bytes)
constexpr size_t WS_COUNT = 0;        // 4 ints: prop, corr, total, done
constexpr size_t WS_M     = 64;       // 8 ints
constexpr size_t WS_SOA   = 256;      // 6 * SOA_ARR floats = 356,352 B
constexpr size_t WS_SUP   = 360448;   // 8 * 32 * ROWPAD * 8 = 3,801,088 B
}

__device__ __constant__ float d_anchw[NA] = {1.3221f, 3.19275f, 5.05587f, 9.47112f, 11.2364f};
__device__ __constant__ float d_anchh[NA] = {1.73145f, 4.00944f, 8.09892f, 4.84053f, 10.0071f};

__device__ inline unsigned long long shflx64(unsigned long long v, int m) {
    int lo = __shfl_xor((int)(unsigned)(v & 0xffffffffull), m, 64);
    int hi = __shfl_xor((int)(unsigned)(v >> 32), m, 64);
    return ((unsigned long long)(unsigned)hi << 32) | (unsigned)lo;
}
// uniform-index 64-bit readlane: ~3 cyc vs ~60-80 cyc for ds_bpermute shuffles
__device__ inline unsigned long long rdlane64(unsigned long long v, int l) {
    unsigned lo = (unsigned)__builtin_amdgcn_readlane((int)(unsigned)(v & 0xffffffffull), l);
    unsigned hi = (unsigned)__builtin_amdgcn_readlane((int)(unsigned)(v >> 32), l);
    return ((unsigned long long)hi << 32) | lo;
}
// Barrier that waits ONLY on LDS (lgkmcnt(0)), leaving global prefetch loads
// in flight across the barrier (AITER-style: vmcnt never drained at barrier).
// 0xC07F = vmcnt(63) | expcnt(7) | lgkmcnt(0) on gfx9-class encoding.
// All cross-wave state in k_sweep lives in LDS, so this is sufficient.
__device__ inline void barrier_lgkm() {
    __asm__ volatile("" ::: "memory");
    __builtin_amdgcn_s_waitcnt(0xC07F);
    __builtin_amdgcn_s_barrier();
    __asm__ volatile("" ::: "memory");
}

// ---- K1: decode + register-blocked bitonic sort + sorted SoA to global ----
__global__ __launch_bounds__(NT1, 1) void k_decode_sort(
    const float* __restrict__ net, float* __restrict__ soa,
    int* __restrict__ Marr, int* __restrict__ counters)
{
    __shared__ unsigned long long skey[SORTN];   // 16 KB
    __shared__ float4 sbox[NBOX];                // 28.9 KB
    __shared__ int sM;
    const int b = blockIdx.x, tid = threadIdx.x;
    const float* op = net + (size_t)b * (NA * 25 * NCELL);
    if (tid == 0) sM = 0;
    if (b == 0 && tid < 4) counters[tid] = 0;    // replaces memset dispatch

    for (int n = tid; n < NBOX; n += NT1) {
        int a = n / NCELL;
        int r = n - a * NCELL;
        int y = r / 19;
        int x = r - y * 19;
        int base = a * 25 * NCELL + r;
        float t0 = op[base];
        float t1 = op[base + 1 * NCELL];
        float t2 = op[base + 2 * NCELL];
        float t3 = op[base + 3 * NCELL];
        float t4 = op[base + 4 * NCELL];
        float cx = (1.0f / (1.0f + expf(-t0)) + (float)x) / 19.0f;
        float cy = (1.0f / (1.0f + expf(-t1)) + (float)y) / 19.0f;
        float bw = expf(t2) * (d_anchw[a] / 19.0f);
        float bh = expf(t3) * (d_anchh[a] / 19.0f);
        float det = 1.0f / (1.0f + expf(-t4));
        sbox[n] = make_float4(cx, cy, bw, bh);
        skey[n] = ((unsigned long long)(~__float_as_uint(det)) << 32) | (unsigned)n;
    }
    for (int n = NBOX + tid; n < SORTN; n += NT1) skey[n] = ~0ull;
    __syncthreads();

    unsigned long long v[8];
    const int base8 = tid << 3;
    auto cas = [&](int x, int y, bool up) {
        unsigned long long a = v[x], c = v[y];
        if ((a > c) == up) { v[x] = c; v[y] = a; }
    };
    {
        #pragma unroll
        for (int p = 0; p < 8; ++p) v[p] = skey[base8 + p];
        cas(0,1,true); cas(2,3,false); cas(4,5,true); cas(6,7,false);
        cas(0,2,true); cas(1,3,true); cas(4,6,false); cas(5,7,false);
        cas(0,1,true); cas(2,3,true); cas(4,5,false); cas(6,7,false);
        bool u8 = ((base8 & 8) == 0);
        cas(0,4,u8); cas(1,5,u8); cas(2,6,u8); cas(3,7,u8);
        cas(0,2,u8); cas(1,3,u8); cas(4,6,u8); cas(5,7,u8);
        cas(0,1,u8); cas(2,3,u8); cas(4,5,u8); cas(6,7,u8);
        #pragma unroll
        for (int p = 0; p < 8; ++p) skey[base8 + p] = v[p];
    }
    __syncthreads();
    for (unsigned k = 16; k <= SORTN; k <<= 1) {
        for (unsigned j = k >> 1; j >= 8; j >>= 1) {
            #pragma unroll
            for (int c = 0; c < 4; ++c) {
                unsigned m = (tid << 2) + c;
                unsigned i = ((m & ~(j - 1)) << 1) | (m & (j - 1));
                unsigned p = i | j;
                bool up = ((i & k) == 0);
                unsigned long long a = skey[i], c2 = skey[p];
                if ((a > c2) == up) { skey[i] = c2; skey[p] = a; }
            }
            __syncthreads();
        }
        {
            #pragma unroll
            for (int p = 0; p < 8; ++p) v[p] = skey[base8 + p];
            bool up = ((base8 & k) == 0);
            cas(0,4,up); cas(1,5,up); cas(2,6,up); cas(3,7,up);
            cas(0,2,up); cas(1,3,up); cas(4,6,up); cas(5,7,up);
            cas(0,1,up); cas(2,3,up); cas(4,5,up); cas(6,7,up);
            #pragma unroll
            for (int p = 0; p < 8; ++p) skey[base8 + p] = v[p];
        }
        __syncthreads();
    }

    float* X1 = soa + 0 * SOA_ARR + b * SOA_STRIDE;
    float* Y1 = soa + 1 * SOA_ARR + b * SOA_STRIDE;
    float* X2 = soa + 2 * SOA_ARR + b * SOA_STRIDE;
    float* Y2 = soa + 3 * SOA_ARR + b * SOA_STRIDE;
    float* Wd = soa + 4 * SOA_ARR + b * SOA_STRIDE;
    float* Hd = soa + 5 * SOA_ARR + b * SOA_STRIDE;
    for (int p = tid; p < NBOX; p += NT1) {
        unsigned long long kk = skey[p];
        int n = (int)(unsigned)(kk & 0xffffffffull);
        float det = __uint_as_float(~(unsigned)(kk >> 32));
        float4 bx = sbox[n];
        X1[p] = bx.x - 0.5f * bx.z;
        Y1[p] = bx.y - 0.5f * bx.w;
        X2[p] = bx.x + 0.5f * bx.z;
        Y2[p] = bx.y + 0.5f * bx.w;
        Wd[p] = bx.z;
        Hd[p] = bx.w;
        if (det > CONF_T) {
            float dn = 0.0f;
            if (p + 1 < NBOX) dn = __uint_as_float(~(unsigned)(skey[p + 1] >> 32));
            if (!(dn > CONF_T)) sM = p + 1;      // unique boundary thread
        }
    }
    __syncthreads();
    if (tid == 0) Marr[b] = sM;
}

// ---- K2: suppression words, transposed supT[b][word][row]; XCD swizzle ----
__global__ __launch_bounds__(256) void k_iou_maskT(
    const float* __restrict__ soa, const int* __restrict__ Marr,
    unsigned long long* __restrict__ supT)
{
    const int blk  = blockIdx.x;
    const int b    = blk & 7;
    const int lane = threadIdx.x & 63;
    const int i    = (blk >> 3) * 4 + (threadIdx.x >> 6);
    const int M = Marr[b];
    if (i >= M) return;
    const float* X1 = soa + 0 * SOA_ARR + b * SOA_STRIDE;
    const float* Y1 = soa + 1 * SOA_ARR + b * SOA_STRIDE;
    const float* X2 = soa + 2 * SOA_ARR + b * SOA_STRIDE;
    const float* Y2 = soa + 3 * SOA_ARR + b * SOA_STRIDE;
    const float* Wd = soa + 4 * SOA_ARR + b * SOA_STRIDE;
    const float* Hd = soa + 5 * SOA_ARR + b * SOA_STRIDE;
    float ax1 = X1[i], ay1 = Y1[i], ax2 = X2[i], ay2 = Y2[i];
    float aw = Wd[i], ah = Hd[i], aarea = aw * ah;
    const int nch = (M + 63) >> 6;
    unsigned long long myw = 0;
    for (int w = 0; w < nch; ++w) {
        int j = (w << 6) + lane;
        bool pred = false;
        if (j > i && j < M) {
            float bw = Wd[j], bh = Hd[j];
            float uw = fmaxf(ax2, X2[j]) - fminf(ax1, X1[j]);
            float uh = fmaxf(ay2, Y2[j]) - fminf(ay1, Y1[j]);
            float cw = aw + bw - uw;
            float ch = ah + bh - uh;
            if (cw > 0.0f && ch > 0.0f) {
                float ca = cw * ch;
                float ua = aarea + bw * bh - ca;
                pred = ca > NMS_T * ua;          // iou > thresh
            }
        }
        unsigned long long m = __ballot(pred);
        if (w == lane) myw = m;
    }
    if (lane < nch)
        supT[((size_t)b * 32 + lane) * ROWPAD + i] = myw;
}

// ---- K3: 16-wave sweep with lgkm-only barriers (global prefetch stays in
// flight across barriers). Wave 0: readlane serial chain. Waves 1-15: owned
// future-words with cross-barrier prefetch. GT match from LDS SoA. ----
__global__ __launch_bounds__(1024, 1) void k_sweep(
    const float* __restrict__ soa, const float* __restrict__ tgt,
    const int* __restrict__ Marr, const unsigned long long* __restrict__ supT,
    int* __restrict__ counters, float* __restrict__ out)
{
    __shared__ float X1s[NBOX], Y1s[NBOX], X2s[NBOX], Y2s[NBOX];
    __shared__ float Wss[NBOX], Hss[NBOX];               // 43.3 KB
    __shared__ unsigned long long rmw[NWMAX], keepw[NWMAX];
    __shared__ int sNV, sCorr, sProp;
    const int b = blockIdx.x, tid = threadIdx.x;
    const int wv = tid >> 6, lane = tid & 63;
    const int M = Marr[b];
    const int nwa = (M + 63) >> 6;
    const unsigned long long* sb = supT + (size_t)b * 32 * ROWPAD;

    if (tid < NWMAX) { rmw[tid] = 0ull; keepw[tid] = 0ull; }
    if (tid == 0) { sCorr = 0; sProp = 0; }

    // stage sorted SoA into LDS (coalesced)
    {
        const float* X1 = soa + 0 * SOA_ARR + b * SOA_STRIDE;
        const float* Y1 = soa + 1 * SOA_ARR + b * SOA_STRIDE;
        const float* X2 = soa + 2 * SOA_ARR + b * SOA_STRIDE;
        const float* Y2 = soa + 3 * SOA_ARR + b * SOA_STRIDE;
        const float* Wd = soa + 4 * SOA_ARR + b * SOA_STRIDE;
        const float* Hd = soa + 5 * SOA_ARR + b * SOA_STRIDE;
        for (int p = tid; p < NBOX; p += 1024) {
            X1s[p] = X1[p]; Y1s[p] = Y1[p];
            X2s[p] = X2[p]; Y2s[p] = Y2[p];
            Wss[p] = Wd[p]; Hss[p] = Hd[p];
        }
    }
    if (wv == 2) {       // GT count via ballot (first row with cx==0)
        float cxv = (lane < TMAX) ? tgt[b * 250 + lane * 5 + 1] : 0.0f;
        unsigned long long bm = __ballot(cxv != 0.0f);
        unsigned long long inv = (~bm) & ((1ull << TMAX) - 1);
        if (lane == 0) sNV = inv ? (__ffsll((long long)inv) - 1) : TMAX;
    }

    // static word ownership: wave wv owns {wv, wv+15} (covers words 1..28)
    const int w1 = (wv >= 1) ? wv : -1;
    const int w2 = (wv >= 1 && wv + 15 <= 28) ? (wv + 15) : -1;
    unsigned long long cur1 = 0, cur2 = 0, diag = 0;
    if (wv == 0 && nwa > 0) diag = sb[lane];                       // tile0 diag
    if (w1 >= 1 && w1 < nwa) cur1 = sb[(size_t)w1 * ROWPAD + lane]; // tile0 col
    if (w2 >= 1 && w2 < nwa) cur2 = sb[(size_t)w2 * ROWPAD + lane];
    barrier_lgkm();

    for (int t = 0; t < nwa; ++t) {
        if (wv == 0) {
            // serial greedy sweep for tile t: pure SALU/readlane chain
            unsigned long long cur = rmw[t];
            int rem = M - (t << 6);
            unsigned long long vm = (rem >= 64) ? ~0ull : ((1ull << rem) - 1ull);
            unsigned long long live = vm & ~cur;
            while (live) {
                int i = __ffsll((long long)live) - 1;       // uniform
                unsigned long long w64 = rdlane64(diag, i); // row i intra-tile word
                cur |= w64;
                live &= ~w64;
                live &= ~(1ull << i);
            }
            unsigned long long kp = vm & ~cur;
            if (lane == 0) keepw[t] = kp;
            int tn = t + 1;
            if (tn < nwa) diag = sb[(size_t)tn * ROWPAD + (tn << 6) + lane];
        }
        barrier_lgkm();                        // keepw[t] visible; vm stays in flight
        {
            unsigned long long kmt = keepw[t]; // LDS broadcast
            if (w1 > t && w1 < nwa) {
                unsigned long long c = ((kmt >> lane) & 1ull) ? cur1 : 0ull;
                c |= shflx64(c, 1);  c |= shflx64(c, 2);  c |= shflx64(c, 4);
                c |= shflx64(c, 8);  c |= shflx64(c, 16); c |= shflx64(c, 32);
                if (lane == 0) rmw[w1] |= c;   // word exclusively owned
            }
            if (w2 > t && w2 < nwa) {
                unsigned long long c = ((kmt >> lane) & 1ull) ? cur2 : 0ull;
                c |= shflx64(c, 1);  c |= shflx64(c, 2);  c |= shflx64(c, 4);
                c |= shflx64(c, 8);  c |= shflx64(c, 16); c |= shflx64(c, 32);
                if (lane == 0) rmw[w2] |= c;
            }
            // prefetch tile t+1 column — consumed after 2 lgkm barriers + sweep
            if (w1 > t + 1 && w1 < nwa) cur1 = sb[(size_t)w1 * ROWPAD + ((t + 1) << 6) + lane];
            if (w2 > t + 1 && w2 < nwa) cur2 = sb[(size_t)w2 * ROWPAD + ((t + 1) << 6) + lane];
        }
        barrier_lgkm();                        // rmw final for sweep(t+1)
    }

    // proposals
    if (wv == 0) {
        unsigned long long kv = (lane < NWMAX) ? keepw[lane] : 0ull;
        int pc = __popcll(kv);
        for (int d = 32; d > 0; d >>= 1) pc += __shfl_down(pc, d, 64);
        if (lane == 0) sProp = pc;
    }

    // ---- GT matching: 16 waves, branchless, LDS SoA ----
    const int nv = sNV;
    for (int t = wv; t < nv; t += 16) {
        const float* g = tgt + b * 250 + t * 5;
        float gcx = g[1], gcy = g[2], gw = g[3], gh = g[4];
        float gx1 = gcx - 0.5f * gw, gx2 = gcx + 0.5f * gw;
        float gy1 = gcy - 0.5f * gh, gy2 = gcy + 0.5f * gh;
        float garea = gw * gh;
        float best = 0.0f;
        for (int j0 = 0; j0 < M; j0 += 64) {
            int j = j0 + lane;
            bool ok = (j < M) && ((keepw[j0 >> 6] >> lane) & 1ull);
            int js = (j < NBOX) ? j : (NBOX - 1);
            float bw = Wss[js], bh = Hss[js];
            float uw = fmaxf(gx2, X2s[js]) - fminf(gx1, X1s[js]);
            float uh = fmaxf(gy2, Y2s[js]) - fminf(gy1, Y1s[js]);
            float cww = gw + bw - uw, chh = gh + bh - uh;
            float ca = (cww > 0.0f && chh > 0.0f) ? cww * chh : 0.0f;
            float ua = garea + bw * bh - ca;
            float iou = ca / ua;
            best = fmaxf(best, ok ? iou : 0.0f);
        }
        for (int d = 32; d > 0; d >>= 1) best = fmaxf(best, __shfl_down(best, d, 64));
        if (lane == 0 && best > IOU_T) atomicAdd(&sCorr, 1);
    }
    barrier_lgkm();

    if (tid == 0) {
        atomicAdd(counters + 0, sProp);
        atomicAdd(counters + 1, sCorr);
        atomicAdd(counters + 2, sNV);
        __threadfence();
        int done = atomicAdd(counters + 3, 1);
        if (done == 7) {
            float prop  = (float)atomicAdd(counters + 0, 0);
            float corr  = (float)atomicAdd(counters + 1, 0);
            float total = (float)atomicAdd(counters + 2, 0);
            float prec = corr / (prop + 1e-6f);
            float rec  = corr / (total + 1e-6f);
            float fs   = 2.0f * prec * rec / (prec + rec + 1e-6f);
            out[0] = total;
            out[1] = prop;
            out[2] = corr;
            out[3] = prec;
            out[4] = rec;
            out[5] = fs;
        }
    }
}

extern "C" void kernel_launch(void* const* d_in, const int* in_sizes, int n_in,
                              void* d_out, int out_size, void* d_ws, size_t ws_size,
                              hipStream_t stream) {
    const float* net = (const float*)d_in[0];   // [8,125,19,19] f32
    const float* tgt = (const float*)d_in[1];   // [8,250] f32
    char* ws = (char*)d_ws;
    int* counters = (int*)(ws + WS_COUNT);
    int* Marr     = (int*)(ws + WS_M);
    float* soa    = (float*)(ws + WS_SOA);
    unsigned long long* supT = (unsigned long long*)(ws + WS_SUP);

    k_decode_sort<<<8, NT1, 0, stream>>>(net, soa, Marr, counters);
    int rowblocks = (NBOX + 3) / 4;              // 452
    k_iou_maskT<<<rowblocks * 8, 256, 0, stream>>>(soa, Marr, supT);
    k_sweep<<<8, 1024, 0, stream>>>(soa, tgt, Marr, supT, counters, (float*)d_out);
}